// Round 11
// baseline (220.674 us; speedup 1.0000x reference)
//
#include <hip/hip_runtime.h>
#include <hip/hip_bf16.h>
#include <stdint.h>

#define KN 32
#define D  128
#define NNODES 20000
#define GRID 2500
#define ITERS 4            // 2 nodes/iter * 4 iters * 2500 blocks = 20000
#define VOCAB 100000
#define CONV_BLOCKS (VOCAB * D / 2048)   // 6250

typedef __bf16 bf16;
typedef __bf16 bf16x8 __attribute__((ext_vector_type(8)));
typedef float  f32x4  __attribute__((ext_vector_type(4)));

// bf16 e_u LDS layout: 8 chunks/node; chunk c (1024 B, one GL2LDS) holds rows
// {c, c+8, c+16, c+24} (256 B each) + 16 B pad -> 520 bf16 elems per chunk.
// Row r -> elem (r&7)*520 + (r>>3)*128.
#define CHUNK_E 520
#define EU_NODE_E (8 * CHUNK_E)      // 4160 bf16 per node
#define H_STRIDE 136                 // bf16 elems; 68 dw, %32=4

#define GL2LDS(src, dst) __builtin_amdgcn_global_load_lds(                 \
    (const __attribute__((address_space(1))) void*)(src),                  \
    (__attribute__((address_space(3))) void*)(dst), 16, 0, 0)

#define MFMA(a, b, c) __builtin_amdgcn_mfma_f32_16x16x32_bf16((a), (b), (c), 0, 0, 0)

// Raw barrier: LDS-hazard only. Does NOT drain vmcnt, so the prefetch
// global_load_lds queue stays in flight across compute phases.
#define LBAR() do {                                                        \
    asm volatile("s_waitcnt lgkmcnt(0)" ::: "memory");                     \
    __builtin_amdgcn_s_barrier();                                          \
    asm volatile("" ::: "memory");                                         \
    __builtin_amdgcn_sched_barrier(0);                                     \
} while (0)

// Build an MFMA bf16x8 fragment from 8 consecutive fp32 (RNE casts).
__device__ __forceinline__ bf16x8 frag_from_f32(const float* __restrict__ p) {
    float4 u0 = *(const float4*)(p);
    float4 u1 = *(const float4*)(p + 4);
    bf16x8 a;
    a[0]=(bf16)u0.x; a[1]=(bf16)u0.y; a[2]=(bf16)u0.z; a[3]=(bf16)u0.w;
    a[4]=(bf16)u1.x; a[5]=(bf16)u1.y; a[6]=(bf16)u1.z; a[7]=(bf16)u1.w;
    return a;
}

// ---------------------------------------------------------------------------
// Merged prologue: blocks [0, CONV_BLOCKS) convert u2e fp32 -> bf16 table
// (normal stores; NT stores regressed badly in R7); blocks [CONV_BLOCKS,+192)
// pack W1/W2 into MFMA B-fragment order.
// w1p fts 0..3 = e_u half (f in [0,128)), fts 4..7 = self half.
// ---------------------------------------------------------------------------
__global__ __launch_bounds__(256) void prep_kernel(
    const float* __restrict__ u2e, const float* __restrict__ W1,
    const float* __restrict__ W2,
    bf16* __restrict__ tbl, bf16* __restrict__ w1p, bf16* __restrict__ w2p)
{
    int b = blockIdx.x;
    if (b < CONV_BLOCKS) {
        size_t i = ((size_t)b * 256 + threadIdx.x) * 8;
        float4 a = *(const float4*)(u2e + i);
        float4 c = *(const float4*)(u2e + i + 4);
        bf16x8 v;
        v[0]=(bf16)a.x; v[1]=(bf16)a.y; v[2]=(bf16)a.z; v[3]=(bf16)a.w;
        v[4]=(bf16)c.x; v[5]=(bf16)c.y; v[6]=(bf16)c.z; v[7]=(bf16)c.w;
        *(bf16x8*)(tbl + i) = v;
    } else {
        int t = (b - CONV_BLOCKS) * 256 + threadIdx.x;
        if (t < 32768) {
            int j = t & 7, lane = (t >> 3) & 63, kt = (t >> 9) & 7, nt = t >> 12;
            int d = nt * 16 + (lane & 15);
            int f = kt * 32 + ((lane >> 4) << 3) + j;
            w1p[t] = (bf16)W1[d * 256 + f];
        } else if (t < 49152) {
            int u = t - 32768;
            int j = u & 7, lane = (u >> 3) & 63, kt = (u >> 9) & 3, nt = u >> 11;
            int e  = nt * 16 + (lane & 15);
            int dd = kt * 32 + ((lane >> 4) << 3) + j;
            w2p[u] = (bf16)W2[e * 128 + dd];
        }
    }
}

// ---------------------------------------------------------------------------
// Main kernel: R10 structure (3 barriers/iter, STAGE-after-barrier, counted
// vmcnt(1), sv hoisted once-per-block, unrolled nd loops) with two epilogue
// trims:
//  (1) att broadcast via LDS (att_s[2][KN], +256 B): the agg loop's 32
//      ds_bpermute/thread (__shfl of att) become 8 ds_read_b128 broadcast
//      reads of a wave-locally staged att row. Same-wave RAW on LDS is
//      in-order; an lgkmcnt(0) guards codegen reordering.
//  (2) __expf in softmax (bounded inputs; absmax tolerance 1.5e-2 >> ulp).
// LDS 54016 B -> still 3 blocks/CU (cap 54613).
// ---------------------------------------------------------------------------
__global__ __launch_bounds__(256, 3) void graphrec_agg_kernel(
    const int*   __restrict__ nodes,
    const int*   __restrict__ neigh_idx,
    const int*   __restrict__ neigh_len,
    const float* __restrict__ u2e,
    const bf16*  __restrict__ u2e_bf,
    const float* __restrict__ b1,
    const float* __restrict__ b2,
    const float* __restrict__ W3,
    const float* __restrict__ b3,
    const bf16*  __restrict__ w1p,
    const bf16*  __restrict__ w2p,
    float*       __restrict__ out)
{
    __shared__ alignas(16) bf16  eu[2][2 * EU_NODE_E];     // 33280 B (dbuf)
    __shared__ alignas(16) float self_f[2][2 * D];         // 2048 B  (dbuf)
    __shared__ alignas(16) bf16  h1[2 * KN * H_STRIDE];    // 17408 B
    __shared__ float lpart[2][4 * KN];                     // 1024 B
    __shared__ alignas(16) float att_s[2][KN];             // 256 B

    const int t    = threadIdx.x;
    const int lane = t & 63;
    const int wave = t >> 6;
    const int ln15 = lane & 15;
    const int quad = lane >> 4;
    const int nt0  = wave * 2;

    const float bias1_0 = b1[nt0 * 16 + ln15];
    const float bias1_1 = b1[(nt0 + 1) * 16 + ln15];
    const float bias2_0 = b2[nt0 * 16 + ln15];
    const float bias2_1 = b2[(nt0 + 1) * 16 + ln15];
    const float w3_0    = W3[nt0 * 16 + ln15];
    const float w3_1    = W3[(nt0 + 1) * 16 + ln15];
    const float b3v     = b3[0];

    // ---- once-per-block self-contribution (8 MFMAs) ----
    // A rows 0..7 = table embeddings of this block's 8 nodes. B = W1 self
    // half (w1p fts 4..7). C layout: col=lane&15, row=(lane>>4)*4+reg ->
    // node j lives in lanes (j>>2)*16+c, reg j&3.
    f32x4 cs0 = {0.f,0.f,0.f,0.f}, cs1 = cs0;
    {
        int nid = nodes[blockIdx.x * 8 + (ln15 & 7)];
        #pragma unroll
        for (int kt = 0; kt < 4; ++kt) {
            bf16x8 a   = *(const bf16x8*)(u2e_bf + (size_t)nid * D + kt * 32 + quad * 8);
            bf16x8 bb0 = *(const bf16x8*)(w1p + (nt0 * 8 + 4 + kt) * 512 + lane * 8);
            bf16x8 bb1 = *(const bf16x8*)(w1p + ((nt0 + 1) * 8 + 4 + kt) * 512 + lane * 8);
            cs0 = MFMA(a, bb0, cs0);
            cs1 = MFMA(a, bb1, cs1);
        }
    }

    // resident weight fragments: W1 e_u half + W2 (64 VGPRs)
    bf16x8 w1e[2][4], w2r[2][4];
    #pragma unroll
    for (int nt = 0; nt < 2; ++nt) {
        #pragma unroll
        for (int ft = 0; ft < 4; ++ft)
            w1e[nt][ft] = *(const bf16x8*)(w1p + ((nt0 + nt) * 8 + ft) * 512 + lane * 8);
        #pragma unroll
        for (int kt = 0; kt < 4; ++kt)
            w2r[nt][kt] = *(const bf16x8*)(w2p + ((nt0 + nt) * 4 + kt) * 512 + lane * 8);
    }

    // prefetch block: counted vmem ops only (idx int4 + 4 GL2LDS; wave0 +1)
    auto STAGE = [&](int jt) {
        const int buf = jt & 1;
        const int nA2 = blockIdx.x * 8 + jt * 2;
        const int gnd = wave >> 1;            // node this wave stages
        const int cb  = (wave & 1) * 4;       // first of its 4 chunks
        const int sA  = nodes[nA2];           // uniform -> s_load (lgkm)
        const int sB  = nodes[nA2 + 1];
        int4 idx4 = *(const int4*)(neigh_idx + (size_t)(nA2 + gnd) * KN + cb + (quad << 3));
        bf16* dst = &eu[buf][gnd * EU_NODE_E + cb * CHUNK_E];
        const size_t col = (size_t)(ln15 << 3);
        GL2LDS(u2e_bf + (size_t)idx4.x * D + col, dst);
        GL2LDS(u2e_bf + (size_t)idx4.y * D + col, dst + CHUNK_E);
        GL2LDS(u2e_bf + (size_t)idx4.z * D + col, dst + 2 * CHUNK_E);
        GL2LDS(u2e_bf + (size_t)idx4.w * D + col, dst + 3 * CHUNK_E);
        if (wave == 0) {                      // selfA||selfB fp32, ONE instr
            int sidx = (lane >> 5) ? sB : sA;
            GL2LDS(u2e + (size_t)sidx * D + ((lane & 31) << 2), &self_f[buf][0]);
        }
    };

    __builtin_amdgcn_sched_barrier(0);
    STAGE(0);

    #pragma unroll 1
    for (int it = 0; it < ITERS; ++it) {
        const int nA   = blockIdx.x * 8 + it * 2;
        const int lenA = neigh_len[nA];       // uniform -> s_load (lgkm)
        const int lenB = neigh_len[nA + 1];

        __builtin_amdgcn_sched_barrier(0);
        // top wait: STAGE(it) complete; tolerate out-store(it-1) in flight.
        if (it == 0) {
            asm volatile("s_waitcnt vmcnt(0)" ::: "memory");
        } else {
            asm volatile("s_waitcnt vmcnt(1)" ::: "memory");
        }
        __builtin_amdgcn_s_barrier();         // also: all waves done agg(it-1)
        asm volatile("" ::: "memory");
        __builtin_amdgcn_sched_barrier(0);
        if (it + 1 < ITERS) STAGE(it + 1);    // safe: slot last read in it-1
        __builtin_amdgcn_sched_barrier(0);

        const bf16*  euIt = &eu[it & 1][0];
        const float* sfIt = &self_f[it & 1][0];

        // sv bias broadcast for nodes 2it (A) and 2it+1 (B):
        // node j = 2it+nd -> reg 2*(it&1)+nd, source lane (it>>1)*16+ln15.
        const bool hi = (it & 1);
        const float selA0 = hi ? cs0[2] : cs0[0];
        const float selB0 = hi ? cs0[3] : cs0[1];
        const float selA1 = hi ? cs1[2] : cs1[0];
        const float selB1 = hi ? cs1[3] : cs1[1];
        const int   srcl  = ((it >> 1) << 4) + ln15;
        const float svA0 = __shfl(selA0, srcl);
        const float svB0 = __shfl(selB0, srcl);
        const float svA1 = __shfl(selA1, srcl);
        const float svB1 = __shfl(selB1, srcl);

        // ---- layer 1, both nodes UNROLLED: independent LDS/MFMA streams ----
        #pragma unroll
        for (int nd = 0; nd < 2; ++nd) {
            const bf16* euN = euIt + nd * EU_NODE_E;
            bf16* h1N = h1 + nd * KN * H_STRIDE;

            f32x4 c00 = {0.f,0.f,0.f,0.f}, c01 = c00, c10 = c00, c11 = c00;
            const int rb = (ln15 & 7) * CHUNK_E + (ln15 >> 3) * 128;
            #pragma unroll
            for (int ft = 0; ft < 4; ++ft) {
                bf16x8 a0 = *(const bf16x8*)(euN + rb + ft * 32 + quad * 8);
                bf16x8 a1 = *(const bf16x8*)(euN + rb + 256 + ft * 32 + quad * 8);
                c00 = MFMA(a0, w1e[0][ft], c00);
                c01 = MFMA(a0, w1e[1][ft], c01);
                c10 = MFMA(a1, w1e[0][ft], c10);
                c11 = MFMA(a1, w1e[1][ft], c11);
            }
            const float s0 = nd ? svB0 : svA0;
            const float s1 = nd ? svB1 : svA1;
            #pragma unroll
            for (int r = 0; r < 4; ++r) {      // relu(c + b1 + sv) -> bf16 LDS
                int row = quad * 4 + r;
                h1N[row * H_STRIDE + nt0 * 16 + ln15]              = (bf16)fmaxf(c00[r] + bias1_0 + s0, 0.f);
                h1N[row * H_STRIDE + (nt0 + 1) * 16 + ln15]        = (bf16)fmaxf(c01[r] + bias1_1 + s1, 0.f);
                h1N[(16 + row) * H_STRIDE + nt0 * 16 + ln15]       = (bf16)fmaxf(c10[r] + bias1_0 + s0, 0.f);
                h1N[(16 + row) * H_STRIDE + (nt0 + 1) * 16 + ln15] = (bf16)fmaxf(c11[r] + bias1_1 + s1, 0.f);
            }
        }
        LBAR();   // h1 ready (lgkm only; prefetch stays in flight)

        // ---- layer 2 + fused logits, both nodes UNROLLED ----
        #pragma unroll
        for (int nd = 0; nd < 2; ++nd) {
            const bf16* h1N = h1 + nd * KN * H_STRIDE;
            f32x4 d00 = {0.f,0.f,0.f,0.f}, d01 = d00, d10 = d00, d11 = d00;
            #pragma unroll
            for (int kt = 0; kt < 4; ++kt) {
                bf16x8 a0 = *(const bf16x8*)(h1N + ln15 * H_STRIDE + kt * 32 + quad * 8);
                bf16x8 a1 = *(const bf16x8*)(h1N + (16 + ln15) * H_STRIDE + kt * 32 + quad * 8);
                d00 = MFMA(a0, w2r[0][kt], d00);
                d01 = MFMA(a0, w2r[1][kt], d01);
                d10 = MFMA(a1, w2r[0][kt], d10);
                d11 = MFMA(a1, w2r[1][kt], d11);
            }
            #pragma unroll
            for (int r = 0; r < 4; ++r) {   // h2 never materialized
                float p0 = w3_0 * fmaxf(d00[r] + bias2_0, 0.f)
                         + w3_1 * fmaxf(d01[r] + bias2_1, 0.f);
                float p1 = w3_0 * fmaxf(d10[r] + bias2_0, 0.f)
                         + w3_1 * fmaxf(d11[r] + bias2_1, 0.f);
                #pragma unroll
                for (int o = 1; o < 16; o <<= 1) {
                    p0 += __shfl_xor(p0, o);
                    p1 += __shfl_xor(p1, o);
                }
                if (ln15 == 0) {
                    lpart[nd][wave * KN + quad * 4 + r]      = p0;
                    lpart[nd][wave * KN + 16 + quad * 4 + r] = p1;
                }
            }
        }
        LBAR();   // lpart ready

        // ---- per-wave softmax + aggregation (wave w: node w>>1, cols (w&1)*64..) ----
        {
            const int nd = wave >> 1;
            const int k  = lane & 31;
            float lg = lpart[nd][k] + lpart[nd][KN + k] + lpart[nd][2 * KN + k]
                     + lpart[nd][3 * KN + k] + b3v;
            const int len = nd ? lenB : lenA;
            bool act = k < len;
            float l = act ? lg : -1e30f;
            float m = l;
            #pragma unroll
            for (int o = 1; o < 32; o <<= 1) m = fmaxf(m, __shfl_xor(m, o));
            float e = act ? __expf(l - m) : 0.f;
            float s = e;
            #pragma unroll
            for (int o = 1; o < 32; o <<= 1) s += __shfl_xor(s, o);
            float att = (s > 0.f) ? (e / s) : 0.f;

            // stage att row in LDS (wave-local; both waves of a node write
            // identical values -> benign). Replaces 32 bpermutes with 8
            // broadcast b128 reads.
            if (lane < 32) att_s[nd][k] = att;
            asm volatile("s_waitcnt lgkmcnt(0)" ::: "memory");

            f32x4 av[8];
            #pragma unroll
            for (int q = 0; q < 8; ++q)
                av[q] = *(const f32x4*)&att_s[nd][q * 4];

            const int d = ((wave & 1) << 6) + lane;
            const bf16* euN = euIt + nd * EU_NODE_E;
            float acc = 0.f;
            #pragma unroll
            for (int k2 = 0; k2 < KN; ++k2) {
                float ev = (float)euN[(k2 & 7) * CHUNK_E + (k2 >> 3) * 128 + (d & 127)];
                acc += av[k2 >> 2][k2 & 3] * ev;
            }
            float sf = sfIt[nd * D + (d & 127)];
            out[(size_t)(nA + nd) * D + (d & 127)] = (len > 0) ? 0.5f * (acc + sf) : sf;
        }
        // no end-of-iteration barrier: next iteration's top barrier covers
        // the eu/self slot reuse (STAGE is issued after it) AND the att_s
        // write-read (att_s is re-written each iter by the same waves).
    }
}

// ---------------------------------------------------------------------------
// Fallback for small ws_size: single-kernel fp32-gather version (R5-proven,
// zero workspace).
// ---------------------------------------------------------------------------
__global__ __launch_bounds__(256, 4) void graphrec_agg_nows(
    const int*   __restrict__ nodes,
    const int*   __restrict__ neigh_idx,
    const int*   __restrict__ neigh_len,
    const float* __restrict__ u2e,
    const float* __restrict__ W1,
    const float* __restrict__ b1,
    const float* __restrict__ W2,
    const float* __restrict__ b2,
    const float* __restrict__ W3,
    const float* __restrict__ b3,
    float*       __restrict__ out)
{
    __shared__ alignas(16) bf16  eu[2 * EU_NODE_E];
    __shared__ alignas(16) float self_f[2 * D];
    __shared__ alignas(16) bf16  h1[2 * KN * H_STRIDE];
    __shared__ float lpart[2][4 * KN];

    const int t    = threadIdx.x;
    const int lane = t & 63;
    const int wave = t >> 6;
    const int ln15 = lane & 15;
    const int quad = lane >> 4;
    const int nt0  = wave * 2;

    const float bias1_0 = b1[nt0 * 16 + ln15];
    const float bias1_1 = b1[(nt0 + 1) * 16 + ln15];
    const float bias2_0 = b2[nt0 * 16 + ln15];
    const float bias2_1 = b2[(nt0 + 1) * 16 + ln15];
    const float w3_0    = W3[nt0 * 16 + ln15];
    const float w3_1    = W3[(nt0 + 1) * 16 + ln15];
    const float b3v     = b3[0];

    const size_t w1rowA = (size_t)(nt0 * 16 + ln15) * 256;
    const size_t w1rowB = (size_t)((nt0 + 1) * 16 + ln15) * 256;
    const size_t w2rowA = (size_t)(nt0 * 16 + ln15) * 128;
    const size_t w2rowB = (size_t)((nt0 + 1) * 16 + ln15) * 128;
    const int    kofs   = quad * 8;

    f32x4 cs0 = {0.f,0.f,0.f,0.f}, cs1 = cs0;
    {
        int nid = nodes[blockIdx.x * 8 + (ln15 & 7)];
        #pragma unroll
        for (int kt = 0; kt < 4; ++kt) {
            bf16x8 a   = frag_from_f32(u2e + (size_t)nid * D + kt * 32 + kofs);
            bf16x8 bb0 = frag_from_f32(W1 + w1rowA + 128 + kt * 32 + kofs);
            bf16x8 bb1 = frag_from_f32(W1 + w1rowB + 128 + kt * 32 + kofs);
            cs0 = MFMA(a, bb0, cs0);
            cs1 = MFMA(a, bb1, cs1);
        }
    }

    bf16x8 w1r[2][4], w2r[2][4];
    #pragma unroll
    for (int ft = 0; ft < 4; ++ft) {
        w1r[0][ft] = frag_from_f32(W1 + w1rowA + ft * 32 + kofs);
        w1r[1][ft] = frag_from_f32(W1 + w1rowB + ft * 32 + kofs);
        w2r[0][ft] = frag_from_f32(W2 + w2rowA + ft * 32 + kofs);
        w2r[1][ft] = frag_from_f32(W2 + w2rowB + ft * 32 + kofs);
    }

    #pragma unroll 1
    for (int it = 0; it < ITERS; ++it) {
        const int nA   = blockIdx.x * 8 + it * 2;
        const int lenA = neigh_len[nA];
        const int lenB = neigh_len[nA + 1];

        {
            const int gnd = wave >> 1;
            const int cb  = (wave & 1) * 4;
            int4 idx4 = *(const int4*)(neigh_idx + (size_t)(nA + gnd) * KN + cb + (quad << 3));
            const size_t col = (size_t)(ln15 << 3);
            float4 v0[4], v1[4];
            {
                const float* s0 = u2e + (size_t)idx4.x * D + col;
                const float* s1 = u2e + (size_t)idx4.y * D + col;
                const float* s2 = u2e + (size_t)idx4.z * D + col;
                const float* s3 = u2e + (size_t)idx4.w * D + col;
                v0[0] = *(const float4*)(s0); v1[0] = *(const float4*)(s0 + 4);
                v0[1] = *(const float4*)(s1); v1[1] = *(const float4*)(s1 + 4);
                v0[2] = *(const float4*)(s2); v1[2] = *(const float4*)(s2 + 4);
                v0[3] = *(const float4*)(s3); v1[3] = *(const float4*)(s3 + 4);
            }
            if (wave == 0) {
                int sidx = nodes[nA + (lane >> 5)];
                GL2LDS(u2e + (size_t)sidx * D + ((lane & 31) << 2), self_f);
            }
            #pragma unroll
            for (int j = 0; j < 4; ++j) {
                bf16x8 w;
                w[0]=(bf16)v0[j].x; w[1]=(bf16)v0[j].y; w[2]=(bf16)v0[j].z; w[3]=(bf16)v0[j].w;
                w[4]=(bf16)v1[j].x; w[5]=(bf16)v1[j].y; w[6]=(bf16)v1[j].z; w[7]=(bf16)v1[j].w;
                *(bf16x8*)(eu + gnd * EU_NODE_E + (cb + j) * CHUNK_E + quad * 128 + ln15 * 8) = w;
            }
        }
        __syncthreads();

        const bool hi = (it & 1);
        const float selA0 = hi ? cs0[2] : cs0[0];
        const float selB0 = hi ? cs0[3] : cs0[1];
        const float selA1 = hi ? cs1[2] : cs1[0];
        const float selB1 = hi ? cs1[3] : cs1[1];
        const int   srcl  = ((it >> 1) << 4) + ln15;
        const float svA0 = __shfl(selA0, srcl);
        const float svB0 = __shfl(selB0, srcl);
        const float svA1 = __shfl(selA1, srcl);
        const float svB1 = __shfl(selB1, srcl);

        #pragma unroll 1
        for (int nd = 0; nd < 2; ++nd) {
            const bf16* euN = eu + nd * EU_NODE_E;
            bf16* h1N = h1 + nd * KN * H_STRIDE;

            f32x4 c00 = {0.f,0.f,0.f,0.f}, c01 = c00, c10 = c00, c11 = c00;
            const int rb = (ln15 & 7) * CHUNK_E + (ln15 >> 3) * 128;
            #pragma unroll
            for (int ft = 0; ft < 4; ++ft) {
                bf16x8 a0 = *(const bf16x8*)(euN + rb + ft * 32 + quad * 8);
                bf16x8 a1 = *(const bf16x8*)(euN + rb + 256 + ft * 32 + quad * 8);
                c00 = MFMA(a0, w1r[0][ft], c00);
                c01 = MFMA(a0, w1r[1][ft], c01);
                c10 = MFMA(a1, w1r[0][ft], c10);
                c11 = MFMA(a1, w1r[1][ft], c11);
            }
            const float s0 = nd ? svB0 : svA0;
            const float s1 = nd ? svB1 : svA1;
            #pragma unroll
            for (int r = 0; r < 4; ++r) {
                int row = quad * 4 + r;
                h1N[row * H_STRIDE + nt0 * 16 + ln15]              = (bf16)fmaxf(c00[r] + bias1_0 + s0, 0.f);
                h1N[row * H_STRIDE + (nt0 + 1) * 16 + ln15]        = (bf16)fmaxf(c01[r] + bias1_1 + s1, 0.f);
                h1N[(16 + row) * H_STRIDE + nt0 * 16 + ln15]       = (bf16)fmaxf(c10[r] + bias1_0 + s0, 0.f);
                h1N[(16 + row) * H_STRIDE + (nt0 + 1) * 16 + ln15] = (bf16)fmaxf(c11[r] + bias1_1 + s1, 0.f);
            }
        }
        __syncthreads();

        #pragma unroll 1
        for (int nd = 0; nd < 2; ++nd) {
            const bf16* h1N = h1 + nd * KN * H_STRIDE;
            f32x4 d00 = {0.f,0.f,0.f,0.f}, d01 = d00, d10 = d00, d11 = d00;
            #pragma unroll
            for (int kt = 0; kt < 4; ++kt) {
                bf16x8 a0 = *(const bf16x8*)(h1N + ln15 * H_STRIDE + kt * 32 + quad * 8);
                bf16x8 a1 = *(const bf16x8*)(h1N + (16 + ln15) * H_STRIDE + kt * 32 + quad * 8);
                d00 = MFMA(a0, w2r[0][kt], d00);
                d01 = MFMA(a0, w2r[1][kt], d01);
                d10 = MFMA(a1, w2r[0][kt], d10);
                d11 = MFMA(a1, w2r[1][kt], d11);
            }
            #pragma unroll
            for (int r = 0; r < 4; ++r) {
                float p0 = w3_0 * fmaxf(d00[r] + bias2_0, 0.f)
                         + w3_1 * fmaxf(d01[r] + bias2_1, 0.f);
                float p1 = w3_0 * fmaxf(d10[r] + bias2_0, 0.f)
                         + w3_1 * fmaxf(d11[r] + bias2_1, 0.f);
                #pragma unroll
                for (int o = 1; o < 16; o <<= 1) {
                    p0 += __shfl_xor(p0, o);
                    p1 += __shfl_xor(p1, o);
                }
                if (ln15 == 0) {
                    lpart[nd][wave * KN + quad * 4 + r]      = p0;
                    lpart[nd][wave * KN + 16 + quad * 4 + r] = p1;
                }
            }
        }
        __syncthreads();

        {
            const int nd = wave >> 1;
            const int k  = lane & 31;
            float lg = lpart[nd][k] + lpart[nd][KN + k] + lpart[nd][2 * KN + k]
                     + lpart[nd][3 * KN + k] + b3v;
            const int len = nd ? lenB : lenA;
            bool act = k < len;
            float l = act ? lg : -1e30f;
            float m = l;
            #pragma unroll
            for (int o = 1; o < 32; o <<= 1) m = fmaxf(m, __shfl_xor(m, o));
            float e = act ? __expf(l - m) : 0.f;
            float s = e;
            #pragma unroll
            for (int o = 1; o < 32; o <<= 1) s += __shfl_xor(s, o);
            float att = (s > 0.f) ? (e / s) : 0.f;

            const int d = ((wave & 1) << 6) + lane;
            const bf16* euN = eu + nd * EU_NODE_E;
            float acc = 0.f;
            #pragma unroll
            for (int k2 = 0; k2 < KN; ++k2) {
                float a  = __shfl(att, k2);
                float ev = (float)euN[(k2 & 7) * CHUNK_E + (k2 >> 3) * 128 + (d & 127)];
                acc += a * ev;
            }
            float sf = self_f[nd * D + (d & 127)];
            out[(size_t)(nA + nd) * D + (d & 127)] = (len > 0) ? 0.5f * (acc + sf) : sf;
        }
        __syncthreads();
    }
}

extern "C" void kernel_launch(void* const* d_in, const int* in_sizes, int n_in,
                              void* d_out, int out_size, void* d_ws, size_t ws_size,
                              hipStream_t stream) {
    const int*   nodes     = (const int*)d_in[0];
    const int*   neigh_idx = (const int*)d_in[1];
    const int*   neigh_len = (const int*)d_in[2];
    const float* u2e       = (const float*)d_in[3];
    const float* W1        = (const float*)d_in[4];
    const float* b1        = (const float*)d_in[5];
    const float* W2        = (const float*)d_in[6];
    const float* b2        = (const float*)d_in[7];
    const float* W3        = (const float*)d_in[8];
    const float* b3        = (const float*)d_in[9];
    float* out = (float*)d_out;

    bf16*  w1p    = (bf16*)d_ws;                                  // 65536 B
    bf16*  w2p    = w1p + 32768;                                  // 32768 B
    bf16*  u2e_bf = (bf16*)((char*)d_ws + 98304);                 // 25.6 MB
    const size_t need = 98304ull + (size_t)VOCAB * D * 2;

    if (ws_size >= need) {
        prep_kernel<<<CONV_BLOCKS + 192, 256, 0, stream>>>(u2e, W1, W2,
                                                           u2e_bf, w1p, w2p);
        graphrec_agg_kernel<<<GRID, 256, 0, stream>>>(nodes, neigh_idx, neigh_len,
                                                      u2e, u2e_bf, b1, b2,
                                                      W3, b3, w1p, w2p, out);
    } else {
        graphrec_agg_nows<<<GRID, 256, 0, stream>>>(nodes, neigh_idx, neigh_len,
                                                    u2e, W1, b1, W2, b2, W3, b3,
                                                    out);
    }
}

// Round 12
// 202.179 us; speedup vs baseline: 1.0915x; 1.0915x over previous
//
#include <hip/hip_runtime.h>
#include <hip/hip_bf16.h>
#include <stdint.h>

#define KN 32
#define D  128
#define NNODES 20000
#define GRID 2500
#define ITERS 4            // 2 nodes/iter * 4 iters * 2500 blocks = 20000
#define VOCAB 100000
#define CONV_BLOCKS (VOCAB * D / 2048)   // 6250

typedef __bf16 bf16;
typedef __bf16 bf16x8 __attribute__((ext_vector_type(8)));
typedef float  f32x4  __attribute__((ext_vector_type(4)));

// bf16 e_u LDS layout: 8 chunks/node; chunk c (1024 B, one GL2LDS) holds rows
// {c, c+8, c+16, c+24} (256 B each) + 16 B pad -> 520 bf16 elems per chunk.
// Row r -> elem (r&7)*520 + (r>>3)*128.
#define CHUNK_E 520
#define EU_NODE_E (8 * CHUNK_E)      // 4160 bf16 per node
#define H_STRIDE 136                 // bf16 elems; 68 dw, %32=4

#define GL2LDS(src, dst) __builtin_amdgcn_global_load_lds(                 \
    (const __attribute__((address_space(1))) void*)(src),                  \
    (__attribute__((address_space(3))) void*)(dst), 16, 0, 0)

#define MFMA(a, b, c) __builtin_amdgcn_mfma_f32_16x16x32_bf16((a), (b), (c), 0, 0, 0)

// Raw barrier: LDS-hazard only. Does NOT drain vmcnt, so the prefetch
// global_load_lds queue stays in flight across compute phases.
#define LBAR() do {                                                        \
    asm volatile("s_waitcnt lgkmcnt(0)" ::: "memory");                     \
    __builtin_amdgcn_s_barrier();                                          \
    asm volatile("" ::: "memory");                                         \
    __builtin_amdgcn_sched_barrier(0);                                     \
} while (0)

// Build an MFMA bf16x8 fragment from 8 consecutive fp32 (RNE casts).
__device__ __forceinline__ bf16x8 frag_from_f32(const float* __restrict__ p) {
    float4 u0 = *(const float4*)(p);
    float4 u1 = *(const float4*)(p + 4);
    bf16x8 a;
    a[0]=(bf16)u0.x; a[1]=(bf16)u0.y; a[2]=(bf16)u0.z; a[3]=(bf16)u0.w;
    a[4]=(bf16)u1.x; a[5]=(bf16)u1.y; a[6]=(bf16)u1.z; a[7]=(bf16)u1.w;
    return a;
}

// ---------------------------------------------------------------------------
// Merged prologue: blocks [0, CONV_BLOCKS) convert u2e fp32 -> bf16 table
// (normal stores; NT stores regressed badly in R7); blocks [CONV_BLOCKS,+192)
// pack W1/W2 into MFMA B-fragment order.
// w1p fts 0..3 = e_u half (f in [0,128)), fts 4..7 = self half.
// ---------------------------------------------------------------------------
__global__ __launch_bounds__(256) void prep_kernel(
    const float* __restrict__ u2e, const float* __restrict__ W1,
    const float* __restrict__ W2,
    bf16* __restrict__ tbl, bf16* __restrict__ w1p, bf16* __restrict__ w2p)
{
    int b = blockIdx.x;
    if (b < CONV_BLOCKS) {
        size_t i = ((size_t)b * 256 + threadIdx.x) * 8;
        float4 a = *(const float4*)(u2e + i);
        float4 c = *(const float4*)(u2e + i + 4);
        bf16x8 v;
        v[0]=(bf16)a.x; v[1]=(bf16)a.y; v[2]=(bf16)a.z; v[3]=(bf16)a.w;
        v[4]=(bf16)c.x; v[5]=(bf16)c.y; v[6]=(bf16)c.z; v[7]=(bf16)c.w;
        *(bf16x8*)(tbl + i) = v;
    } else {
        int t = (b - CONV_BLOCKS) * 256 + threadIdx.x;
        if (t < 32768) {
            int j = t & 7, lane = (t >> 3) & 63, kt = (t >> 9) & 7, nt = t >> 12;
            int d = nt * 16 + (lane & 15);
            int f = kt * 32 + ((lane >> 4) << 3) + j;
            w1p[t] = (bf16)W1[d * 256 + f];
        } else if (t < 49152) {
            int u = t - 32768;
            int j = u & 7, lane = (u >> 3) & 63, kt = (u >> 9) & 3, nt = u >> 11;
            int e  = nt * 16 + (lane & 15);
            int dd = kt * 32 + ((lane >> 4) << 3) + j;
            w2p[u] = (bf16)W2[e * 128 + dd];
        }
    }
}

// ---------------------------------------------------------------------------
// Main kernel: R10 structure (3 barriers/iter, STAGE-after-barrier, counted
// vmcnt(1), sv hoisted once-per-block, unrolled nd loops) + epilogue trims,
// with the R11 lesson applied: LDS is EXACTLY at the 3-blocks/CU boundary
// (53760 B); adding even 256 B dropped to 2 blocks/CU (-17% perf). So the
// att broadcast array is ALIASED into h1's first 256 B (h1 is dead during
// phase 3: last read finished before LBAR-2, next write after the next
// top barrier). Cross-wave double-write of att is value-identical (benign);
// own-wave write->read guarded by lgkmcnt(0). __expf kept (VALU trim).
// LDS 53760 B -> 3 blocks/CU.
// ---------------------------------------------------------------------------
__global__ __launch_bounds__(256, 3) void graphrec_agg_kernel(
    const int*   __restrict__ nodes,
    const int*   __restrict__ neigh_idx,
    const int*   __restrict__ neigh_len,
    const float* __restrict__ u2e,
    const bf16*  __restrict__ u2e_bf,
    const float* __restrict__ b1,
    const float* __restrict__ b2,
    const float* __restrict__ W3,
    const float* __restrict__ b3,
    const bf16*  __restrict__ w1p,
    const bf16*  __restrict__ w2p,
    float*       __restrict__ out)
{
    __shared__ alignas(16) bf16  eu[2][2 * EU_NODE_E];     // 33280 B (dbuf)
    __shared__ alignas(16) float self_f[2][2 * D];         // 2048 B  (dbuf)
    __shared__ alignas(16) bf16  h1[2 * KN * H_STRIDE];    // 17408 B
    __shared__ float lpart[2][4 * KN];                     // 1024 B

    float* att_alias = (float*)h1;   // 2*KN floats, live only in phase 3

    const int t    = threadIdx.x;
    const int lane = t & 63;
    const int wave = t >> 6;
    const int ln15 = lane & 15;
    const int quad = lane >> 4;
    const int nt0  = wave * 2;

    const float bias1_0 = b1[nt0 * 16 + ln15];
    const float bias1_1 = b1[(nt0 + 1) * 16 + ln15];
    const float bias2_0 = b2[nt0 * 16 + ln15];
    const float bias2_1 = b2[(nt0 + 1) * 16 + ln15];
    const float w3_0    = W3[nt0 * 16 + ln15];
    const float w3_1    = W3[(nt0 + 1) * 16 + ln15];
    const float b3v     = b3[0];

    // ---- once-per-block self-contribution (8 MFMAs) ----
    // A rows 0..7 = table embeddings of this block's 8 nodes. B = W1 self
    // half (w1p fts 4..7). C layout: col=lane&15, row=(lane>>4)*4+reg ->
    // node j lives in lanes (j>>2)*16+c, reg j&3.
    f32x4 cs0 = {0.f,0.f,0.f,0.f}, cs1 = cs0;
    {
        int nid = nodes[blockIdx.x * 8 + (ln15 & 7)];
        #pragma unroll
        for (int kt = 0; kt < 4; ++kt) {
            bf16x8 a   = *(const bf16x8*)(u2e_bf + (size_t)nid * D + kt * 32 + quad * 8);
            bf16x8 bb0 = *(const bf16x8*)(w1p + (nt0 * 8 + 4 + kt) * 512 + lane * 8);
            bf16x8 bb1 = *(const bf16x8*)(w1p + ((nt0 + 1) * 8 + 4 + kt) * 512 + lane * 8);
            cs0 = MFMA(a, bb0, cs0);
            cs1 = MFMA(a, bb1, cs1);
        }
    }

    // resident weight fragments: W1 e_u half + W2 (64 VGPRs)
    bf16x8 w1e[2][4], w2r[2][4];
    #pragma unroll
    for (int nt = 0; nt < 2; ++nt) {
        #pragma unroll
        for (int ft = 0; ft < 4; ++ft)
            w1e[nt][ft] = *(const bf16x8*)(w1p + ((nt0 + nt) * 8 + ft) * 512 + lane * 8);
        #pragma unroll
        for (int kt = 0; kt < 4; ++kt)
            w2r[nt][kt] = *(const bf16x8*)(w2p + ((nt0 + nt) * 4 + kt) * 512 + lane * 8);
    }

    // prefetch block: counted vmem ops only (idx int4 + 4 GL2LDS; wave0 +1)
    auto STAGE = [&](int jt) {
        const int buf = jt & 1;
        const int nA2 = blockIdx.x * 8 + jt * 2;
        const int gnd = wave >> 1;            // node this wave stages
        const int cb  = (wave & 1) * 4;       // first of its 4 chunks
        const int sA  = nodes[nA2];           // uniform -> s_load (lgkm)
        const int sB  = nodes[nA2 + 1];
        int4 idx4 = *(const int4*)(neigh_idx + (size_t)(nA2 + gnd) * KN + cb + (quad << 3));
        bf16* dst = &eu[buf][gnd * EU_NODE_E + cb * CHUNK_E];
        const size_t col = (size_t)(ln15 << 3);
        GL2LDS(u2e_bf + (size_t)idx4.x * D + col, dst);
        GL2LDS(u2e_bf + (size_t)idx4.y * D + col, dst + CHUNK_E);
        GL2LDS(u2e_bf + (size_t)idx4.z * D + col, dst + 2 * CHUNK_E);
        GL2LDS(u2e_bf + (size_t)idx4.w * D + col, dst + 3 * CHUNK_E);
        if (wave == 0) {                      // selfA||selfB fp32, ONE instr
            int sidx = (lane >> 5) ? sB : sA;
            GL2LDS(u2e + (size_t)sidx * D + ((lane & 31) << 2), &self_f[buf][0]);
        }
    };

    __builtin_amdgcn_sched_barrier(0);
    STAGE(0);

    #pragma unroll 1
    for (int it = 0; it < ITERS; ++it) {
        const int nA   = blockIdx.x * 8 + it * 2;
        const int lenA = neigh_len[nA];       // uniform -> s_load (lgkm)
        const int lenB = neigh_len[nA + 1];

        __builtin_amdgcn_sched_barrier(0);
        // top wait: STAGE(it) complete; tolerate out-store(it-1) in flight.
        if (it == 0) {
            asm volatile("s_waitcnt vmcnt(0)" ::: "memory");
        } else {
            asm volatile("s_waitcnt vmcnt(1)" ::: "memory");
        }
        __builtin_amdgcn_s_barrier();         // also: all waves done agg(it-1)
        asm volatile("" ::: "memory");
        __builtin_amdgcn_sched_barrier(0);
        if (it + 1 < ITERS) STAGE(it + 1);    // safe: slot last read in it-1
        __builtin_amdgcn_sched_barrier(0);

        const bf16*  euIt = &eu[it & 1][0];
        const float* sfIt = &self_f[it & 1][0];

        // sv bias broadcast for nodes 2it (A) and 2it+1 (B):
        // node j = 2it+nd -> reg 2*(it&1)+nd, source lane (it>>1)*16+ln15.
        const bool hi = (it & 1);
        const float selA0 = hi ? cs0[2] : cs0[0];
        const float selB0 = hi ? cs0[3] : cs0[1];
        const float selA1 = hi ? cs1[2] : cs1[0];
        const float selB1 = hi ? cs1[3] : cs1[1];
        const int   srcl  = ((it >> 1) << 4) + ln15;
        const float svA0 = __shfl(selA0, srcl);
        const float svB0 = __shfl(selB0, srcl);
        const float svA1 = __shfl(selA1, srcl);
        const float svB1 = __shfl(selB1, srcl);

        // ---- layer 1, both nodes UNROLLED: independent LDS/MFMA streams ----
        #pragma unroll
        for (int nd = 0; nd < 2; ++nd) {
            const bf16* euN = euIt + nd * EU_NODE_E;
            bf16* h1N = h1 + nd * KN * H_STRIDE;

            f32x4 c00 = {0.f,0.f,0.f,0.f}, c01 = c00, c10 = c00, c11 = c00;
            const int rb = (ln15 & 7) * CHUNK_E + (ln15 >> 3) * 128;
            #pragma unroll
            for (int ft = 0; ft < 4; ++ft) {
                bf16x8 a0 = *(const bf16x8*)(euN + rb + ft * 32 + quad * 8);
                bf16x8 a1 = *(const bf16x8*)(euN + rb + 256 + ft * 32 + quad * 8);
                c00 = MFMA(a0, w1e[0][ft], c00);
                c01 = MFMA(a0, w1e[1][ft], c01);
                c10 = MFMA(a1, w1e[0][ft], c10);
                c11 = MFMA(a1, w1e[1][ft], c11);
            }
            const float s0 = nd ? svB0 : svA0;
            const float s1 = nd ? svB1 : svA1;
            #pragma unroll
            for (int r = 0; r < 4; ++r) {      // relu(c + b1 + sv) -> bf16 LDS
                int row = quad * 4 + r;
                h1N[row * H_STRIDE + nt0 * 16 + ln15]              = (bf16)fmaxf(c00[r] + bias1_0 + s0, 0.f);
                h1N[row * H_STRIDE + (nt0 + 1) * 16 + ln15]        = (bf16)fmaxf(c01[r] + bias1_1 + s1, 0.f);
                h1N[(16 + row) * H_STRIDE + nt0 * 16 + ln15]       = (bf16)fmaxf(c10[r] + bias1_0 + s0, 0.f);
                h1N[(16 + row) * H_STRIDE + (nt0 + 1) * 16 + ln15] = (bf16)fmaxf(c11[r] + bias1_1 + s1, 0.f);
            }
        }
        LBAR();   // h1 ready (lgkm only; prefetch stays in flight)

        // ---- layer 2 + fused logits, both nodes UNROLLED ----
        #pragma unroll
        for (int nd = 0; nd < 2; ++nd) {
            const bf16* h1N = h1 + nd * KN * H_STRIDE;
            f32x4 d00 = {0.f,0.f,0.f,0.f}, d01 = d00, d10 = d00, d11 = d00;
            #pragma unroll
            for (int kt = 0; kt < 4; ++kt) {
                bf16x8 a0 = *(const bf16x8*)(h1N + ln15 * H_STRIDE + kt * 32 + quad * 8);
                bf16x8 a1 = *(const bf16x8*)(h1N + (16 + ln15) * H_STRIDE + kt * 32 + quad * 8);
                d00 = MFMA(a0, w2r[0][kt], d00);
                d01 = MFMA(a0, w2r[1][kt], d01);
                d10 = MFMA(a1, w2r[0][kt], d10);
                d11 = MFMA(a1, w2r[1][kt], d11);
            }
            #pragma unroll
            for (int r = 0; r < 4; ++r) {   // h2 never materialized
                float p0 = w3_0 * fmaxf(d00[r] + bias2_0, 0.f)
                         + w3_1 * fmaxf(d01[r] + bias2_1, 0.f);
                float p1 = w3_0 * fmaxf(d10[r] + bias2_0, 0.f)
                         + w3_1 * fmaxf(d11[r] + bias2_1, 0.f);
                #pragma unroll
                for (int o = 1; o < 16; o <<= 1) {
                    p0 += __shfl_xor(p0, o);
                    p1 += __shfl_xor(p1, o);
                }
                if (ln15 == 0) {
                    lpart[nd][wave * KN + quad * 4 + r]      = p0;
                    lpart[nd][wave * KN + 16 + quad * 4 + r] = p1;
                }
            }
        }
        LBAR();   // lpart ready (h1 now dead until next iteration)

        // ---- per-wave softmax + aggregation (wave w: node w>>1, cols (w&1)*64..) ----
        {
            const int nd = wave >> 1;
            const int k  = lane & 31;
            float lg = lpart[nd][k] + lpart[nd][KN + k] + lpart[nd][2 * KN + k]
                     + lpart[nd][3 * KN + k] + b3v;
            const int len = nd ? lenB : lenA;
            bool act = k < len;
            float l = act ? lg : -1e30f;
            float m = l;
            #pragma unroll
            for (int o = 1; o < 32; o <<= 1) m = fmaxf(m, __shfl_xor(m, o));
            float e = act ? __expf(l - m) : 0.f;
            float s = e;
            #pragma unroll
            for (int o = 1; o < 32; o <<= 1) s += __shfl_xor(s, o);
            float att = (s > 0.f) ? (e / s) : 0.f;

            // stage att row in dead h1 space (zero LDS growth — R11 lesson:
            // +256 B real LDS dropped occupancy 3->2 blocks/CU). Both waves
            // of a node write identical values (benign); own write->read
            // ordered by lgkmcnt(0). Replaces 32 bpermutes with 8 b128
            // broadcast reads.
            if (lane < 32) att_alias[nd * KN + k] = att;
            asm volatile("s_waitcnt lgkmcnt(0)" ::: "memory");

            f32x4 av[8];
            #pragma unroll
            for (int q = 0; q < 8; ++q)
                av[q] = *(const f32x4*)&att_alias[nd * KN + q * 4];

            const int d = ((wave & 1) << 6) + lane;
            const bf16* euN = euIt + nd * EU_NODE_E;
            float acc = 0.f;
            #pragma unroll
            for (int k2 = 0; k2 < KN; ++k2) {
                float ev = (float)euN[(k2 & 7) * CHUNK_E + (k2 >> 3) * 128 + (d & 127)];
                acc += av[k2 >> 2][k2 & 3] * ev;
            }
            float sf = sfIt[nd * D + (d & 127)];
            out[(size_t)(nA + nd) * D + (d & 127)] = (len > 0) ? 0.5f * (acc + sf) : sf;
        }
        // no end-of-iteration barrier: next iteration's top barrier covers
        // the eu/self slot reuse AND h1/att_alias reuse (phase-1 writes to
        // h1 happen only after all waves pass the next top barrier).
    }
}

// ---------------------------------------------------------------------------
// Fallback for small ws_size: single-kernel fp32-gather version (R5-proven,
// zero workspace).
// ---------------------------------------------------------------------------
__global__ __launch_bounds__(256, 4) void graphrec_agg_nows(
    const int*   __restrict__ nodes,
    const int*   __restrict__ neigh_idx,
    const int*   __restrict__ neigh_len,
    const float* __restrict__ u2e,
    const float* __restrict__ W1,
    const float* __restrict__ b1,
    const float* __restrict__ W2,
    const float* __restrict__ b2,
    const float* __restrict__ W3,
    const float* __restrict__ b3,
    float*       __restrict__ out)
{
    __shared__ alignas(16) bf16  eu[2 * EU_NODE_E];
    __shared__ alignas(16) float self_f[2 * D];
    __shared__ alignas(16) bf16  h1[2 * KN * H_STRIDE];
    __shared__ float lpart[2][4 * KN];

    const int t    = threadIdx.x;
    const int lane = t & 63;
    const int wave = t >> 6;
    const int ln15 = lane & 15;
    const int quad = lane >> 4;
    const int nt0  = wave * 2;

    const float bias1_0 = b1[nt0 * 16 + ln15];
    const float bias1_1 = b1[(nt0 + 1) * 16 + ln15];
    const float bias2_0 = b2[nt0 * 16 + ln15];
    const float bias2_1 = b2[(nt0 + 1) * 16 + ln15];
    const float w3_0    = W3[nt0 * 16 + ln15];
    const float w3_1    = W3[(nt0 + 1) * 16 + ln15];
    const float b3v     = b3[0];

    const size_t w1rowA = (size_t)(nt0 * 16 + ln15) * 256;
    const size_t w1rowB = (size_t)((nt0 + 1) * 16 + ln15) * 256;
    const size_t w2rowA = (size_t)(nt0 * 16 + ln15) * 128;
    const size_t w2rowB = (size_t)((nt0 + 1) * 16 + ln15) * 128;
    const int    kofs   = quad * 8;

    f32x4 cs0 = {0.f,0.f,0.f,0.f}, cs1 = cs0;
    {
        int nid = nodes[blockIdx.x * 8 + (ln15 & 7)];
        #pragma unroll
        for (int kt = 0; kt < 4; ++kt) {
            bf16x8 a   = frag_from_f32(u2e + (size_t)nid * D + kt * 32 + kofs);
            bf16x8 bb0 = frag_from_f32(W1 + w1rowA + 128 + kt * 32 + kofs);
            bf16x8 bb1 = frag_from_f32(W1 + w1rowB + 128 + kt * 32 + kofs);
            cs0 = MFMA(a, bb0, cs0);
            cs1 = MFMA(a, bb1, cs1);
        }
    }

    bf16x8 w1r[2][4], w2r[2][4];
    #pragma unroll
    for (int ft = 0; ft < 4; ++ft) {
        w1r[0][ft] = frag_from_f32(W1 + w1rowA + ft * 32 + kofs);
        w1r[1][ft] = frag_from_f32(W1 + w1rowB + ft * 32 + kofs);
        w2r[0][ft] = frag_from_f32(W2 + w2rowA + ft * 32 + kofs);
        w2r[1][ft] = frag_from_f32(W2 + w2rowB + ft * 32 + kofs);
    }

    #pragma unroll 1
    for (int it = 0; it < ITERS; ++it) {
        const int nA   = blockIdx.x * 8 + it * 2;
        const int lenA = neigh_len[nA];
        const int lenB = neigh_len[nA + 1];

        {
            const int gnd = wave >> 1;
            const int cb  = (wave & 1) * 4;
            int4 idx4 = *(const int4*)(neigh_idx + (size_t)(nA + gnd) * KN + cb + (quad << 3));
            const size_t col = (size_t)(ln15 << 3);
            float4 v0[4], v1[4];
            {
                const float* s0 = u2e + (size_t)idx4.x * D + col;
                const float* s1 = u2e + (size_t)idx4.y * D + col;
                const float* s2 = u2e + (size_t)idx4.z * D + col;
                const float* s3 = u2e + (size_t)idx4.w * D + col;
                v0[0] = *(const float4*)(s0); v1[0] = *(const float4*)(s0 + 4);
                v0[1] = *(const float4*)(s1); v1[1] = *(const float4*)(s1 + 4);
                v0[2] = *(const float4*)(s2); v1[2] = *(const float4*)(s2 + 4);
                v0[3] = *(const float4*)(s3); v1[3] = *(const float4*)(s3 + 4);
            }
            if (wave == 0) {
                int sidx = nodes[nA + (lane >> 5)];
                GL2LDS(u2e + (size_t)sidx * D + ((lane & 31) << 2), self_f);
            }
            #pragma unroll
            for (int j = 0; j < 4; ++j) {
                bf16x8 w;
                w[0]=(bf16)v0[j].x; w[1]=(bf16)v0[j].y; w[2]=(bf16)v0[j].z; w[3]=(bf16)v0[j].w;
                w[4]=(bf16)v1[j].x; w[5]=(bf16)v1[j].y; w[6]=(bf16)v1[j].z; w[7]=(bf16)v1[j].w;
                *(bf16x8*)(eu + gnd * EU_NODE_E + (cb + j) * CHUNK_E + quad * 128 + ln15 * 8) = w;
            }
        }
        __syncthreads();

        const bool hi = (it & 1);
        const float selA0 = hi ? cs0[2] : cs0[0];
        const float selB0 = hi ? cs0[3] : cs0[1];
        const float selA1 = hi ? cs1[2] : cs1[0];
        const float selB1 = hi ? cs1[3] : cs1[1];
        const int   srcl  = ((it >> 1) << 4) + ln15;
        const float svA0 = __shfl(selA0, srcl);
        const float svB0 = __shfl(selB0, srcl);
        const float svA1 = __shfl(selA1, srcl);
        const float svB1 = __shfl(selB1, srcl);

        #pragma unroll 1
        for (int nd = 0; nd < 2; ++nd) {
            const bf16* euN = eu + nd * EU_NODE_E;
            bf16* h1N = h1 + nd * KN * H_STRIDE;

            f32x4 c00 = {0.f,0.f,0.f,0.f}, c01 = c00, c10 = c00, c11 = c00;
            const int rb = (ln15 & 7) * CHUNK_E + (ln15 >> 3) * 128;
            #pragma unroll
            for (int ft = 0; ft < 4; ++ft) {
                bf16x8 a0 = *(const bf16x8*)(euN + rb + ft * 32 + quad * 8);
                bf16x8 a1 = *(const bf16x8*)(euN + rb + 256 + ft * 32 + quad * 8);
                c00 = MFMA(a0, w1r[0][ft], c00);
                c01 = MFMA(a0, w1r[1][ft], c01);
                c10 = MFMA(a1, w1r[0][ft], c10);
                c11 = MFMA(a1, w1r[1][ft], c11);
            }
            const float s0 = nd ? svB0 : svA0;
            const float s1 = nd ? svB1 : svA1;
            #pragma unroll
            for (int r = 0; r < 4; ++r) {
                int row = quad * 4 + r;
                h1N[row * H_STRIDE + nt0 * 16 + ln15]              = (bf16)fmaxf(c00[r] + bias1_0 + s0, 0.f);
                h1N[row * H_STRIDE + (nt0 + 1) * 16 + ln15]        = (bf16)fmaxf(c01[r] + bias1_1 + s1, 0.f);
                h1N[(16 + row) * H_STRIDE + nt0 * 16 + ln15]       = (bf16)fmaxf(c10[r] + bias1_0 + s0, 0.f);
                h1N[(16 + row) * H_STRIDE + (nt0 + 1) * 16 + ln15] = (bf16)fmaxf(c11[r] + bias1_1 + s1, 0.f);
            }
        }
        __syncthreads();

        #pragma unroll 1
        for (int nd = 0; nd < 2; ++nd) {
            const bf16* h1N = h1 + nd * KN * H_STRIDE;
            f32x4 d00 = {0.f,0.f,0.f,0.f}, d01 = d00, d10 = d00, d11 = d00;
            #pragma unroll
            for (int kt = 0; kt < 4; ++kt) {
                bf16x8 a0 = *(const bf16x8*)(h1N + ln15 * H_STRIDE + kt * 32 + quad * 8);
                bf16x8 a1 = *(const bf16x8*)(h1N + (16 + ln15) * H_STRIDE + kt * 32 + quad * 8);
                d00 = MFMA(a0, w2r[0][kt], d00);
                d01 = MFMA(a0, w2r[1][kt], d01);
                d10 = MFMA(a1, w2r[0][kt], d10);
                d11 = MFMA(a1, w2r[1][kt], d11);
            }
            #pragma unroll
            for (int r = 0; r < 4; ++r) {
                float p0 = w3_0 * fmaxf(d00[r] + bias2_0, 0.f)
                         + w3_1 * fmaxf(d01[r] + bias2_1, 0.f);
                float p1 = w3_0 * fmaxf(d10[r] + bias2_0, 0.f)
                         + w3_1 * fmaxf(d11[r] + bias2_1, 0.f);
                #pragma unroll
                for (int o = 1; o < 16; o <<= 1) {
                    p0 += __shfl_xor(p0, o);
                    p1 += __shfl_xor(p1, o);
                }
                if (ln15 == 0) {
                    lpart[nd][wave * KN + quad * 4 + r]      = p0;
                    lpart[nd][wave * KN + 16 + quad * 4 + r] = p1;
                }
            }
        }
        __syncthreads();

        {
            const int nd = wave >> 1;
            const int k  = lane & 31;
            float lg = lpart[nd][k] + lpart[nd][KN + k] + lpart[nd][2 * KN + k]
                     + lpart[nd][3 * KN + k] + b3v;
            const int len = nd ? lenB : lenA;
            bool act = k < len;
            float l = act ? lg : -1e30f;
            float m = l;
            #pragma unroll
            for (int o = 1; o < 32; o <<= 1) m = fmaxf(m, __shfl_xor(m, o));
            float e = act ? __expf(l - m) : 0.f;
            float s = e;
            #pragma unroll
            for (int o = 1; o < 32; o <<= 1) s += __shfl_xor(s, o);
            float att = (s > 0.f) ? (e / s) : 0.f;

            const int d = ((wave & 1) << 6) + lane;
            const bf16* euN = eu + nd * EU_NODE_E;
            float acc = 0.f;
            #pragma unroll
            for (int k2 = 0; k2 < KN; ++k2) {
                float a  = __shfl(att, k2);
                float ev = (float)euN[(k2 & 7) * CHUNK_E + (k2 >> 3) * 128 + (d & 127)];
                acc += a * ev;
            }
            float sf = self_f[nd * D + (d & 127)];
            out[(size_t)(nA + nd) * D + (d & 127)] = (len > 0) ? 0.5f * (acc + sf) : sf;
        }
        __syncthreads();
    }
}

extern "C" void kernel_launch(void* const* d_in, const int* in_sizes, int n_in,
                              void* d_out, int out_size, void* d_ws, size_t ws_size,
                              hipStream_t stream) {
    const int*   nodes     = (const int*)d_in[0];
    const int*   neigh_idx = (const int*)d_in[1];
    const int*   neigh_len = (const int*)d_in[2];
    const float* u2e       = (const float*)d_in[3];
    const float* W1        = (const float*)d_in[4];
    const float* b1        = (const float*)d_in[5];
    const float* W2        = (const float*)d_in[6];
    const float* b2        = (const float*)d_in[7];
    const float* W3        = (const float*)d_in[8];
    const float* b3        = (const float*)d_in[9];
    float* out = (float*)d_out;

    bf16*  w1p    = (bf16*)d_ws;                                  // 65536 B
    bf16*  w2p    = w1p + 32768;                                  // 32768 B
    bf16*  u2e_bf = (bf16*)((char*)d_ws + 98304);                 // 25.6 MB
    const size_t need = 98304ull + (size_t)VOCAB * D * 2;

    if (ws_size >= need) {
        prep_kernel<<<CONV_BLOCKS + 192, 256, 0, stream>>>(u2e, W1, W2,
                                                           u2e_bf, w1p, w2p);
        graphrec_agg_kernel<<<GRID, 256, 0, stream>>>(nodes, neigh_idx, neigh_len,
                                                      u2e, u2e_bf, b1, b2,
                                                      W3, b3, w1p, w2p, out);
    } else {
        graphrec_agg_nows<<<GRID, 256, 0, stream>>>(nodes, neigh_idx, neigh_len,
                                                    u2e, W1, b1, W2, b2, W3, b3,
                                                    out);
    }
}